// Round 14
// baseline (991.634 us; speedup 1.0000x reference)
//
#include <hip/hip_runtime.h>
#include <hip/hip_bf16.h>

typedef __attribute__((ext_vector_type(8))) short bf16x8;
typedef __attribute__((ext_vector_type(4))) float f32x4;

#define NBATCH 4096
#define SEQT 181
#define NFEAT 12
#define HDIM 128
#define ROWS 16
#define LSTR 136
#define OUTSTRIDE (SEQT*NFEAT)

#define WFRAG_ELEMS 262144
#define WOUT_ELEMS  4096
#define BIAS_F32OFF (532480/4)
#define BOUT_F32OFF (536576/4)
#define BBF16_U16OFF 268320

#define ACT_OFF  131072
#define BIAS_OFF 157184
#define BOUT_OFF 161280
#define SMEM_BYTES 161344

#define SSIG (-1.442695041f)
#define STANH (-2.885390082f)

#define FBAR() asm volatile("s_waitcnt lgkmcnt(0)\n\ts_barrier" ::: "memory")
#define MF(W,B,C) __builtin_amdgcn_mfma_f32_16x16x32_bf16((W),(B),(C),0,0,0)

__device__ __forceinline__ float fsig2(float xs) {
  return __builtin_amdgcn_rcpf(1.0f + __builtin_amdgcn_exp2f(xs));
}
__device__ __forceinline__ unsigned short f2bf(float x) {
  __hip_bfloat16 h = __float2bfloat16(x);
  return __builtin_bit_cast(unsigned short, h);
}
__device__ __forceinline__ float bf2f(short u) {
  return __builtin_bit_cast(float, ((unsigned)(unsigned short)u) << 16);
}

// ---------------- setup: repack weights into MFMA fragment order (bf16), pre-scaled ----------------
__global__ void setup_kernel(const float* __restrict__ Wih0, const float* __restrict__ Whh0,
                             const float* __restrict__ bih0, const float* __restrict__ bhh0,
                             const float* __restrict__ Wih1, const float* __restrict__ Whh1,
                             const float* __restrict__ bih1, const float* __restrict__ bhh1,
                             const float* __restrict__ Wo,   const float* __restrict__ bo,
                             unsigned short* __restrict__ ws)
{
  int idx = blockIdx.x * blockDim.x + threadIdx.x;
  if (idx < WFRAG_ELEMS) {
    int e = idx & 7, lane = (idx >> 3) & 63, s = (idx >> 9) & 7, g = (idx >> 12) & 3,
        w = (idx >> 14) & 7, l = idx >> 17;
    int row = g * 128 + w * 16 + (lane & 15);
    int k   = s * 32 + (lane >> 4) * 8 + e;
    const float* Wih = l ? Wih1 : Wih0;
    const float* Whh = l ? Whh1 : Whh0;
    float v = (k < HDIM) ? Wih[row * HDIM + k] : Whh[row * HDIM + (k - HDIM)];
    float sc = (g == 2) ? STANH : SSIG;
    ws[idx] = f2bf(v * sc);
  } else if (idx < WFRAG_ELEMS + WOUT_ELEMS) {
    int i2 = idx - WFRAG_ELEMS;
    int e = i2 & 7, lane = (i2 >> 3) & 63, s = i2 >> 9;
    int c = lane & 15;
    int k = s * 32 + (lane >> 4) * 8 + e;
    float v = (c < NFEAT) ? Wo[c * 256 + k] * SSIG : 0.0f;
    ws[idx] = f2bf(v);
  } else if (idx < WFRAG_ELEMS + WOUT_ELEMS + 1024) {
    int i3 = idx - (WFRAG_ELEMS + WOUT_ELEMS);
    int l = i3 >> 9, r = i3 & 511;
    float v = l ? (bih1[r] + bhh1[r]) : (bih0[r] + bhh0[r]);
    reinterpret_cast<float*>(ws)[BIAS_F32OFF + i3] = v;
  } else if (idx < WFRAG_ELEMS + WOUT_ELEMS + 1024 + 16) {
    int i4 = idx - (WFRAG_ELEMS + WOUT_ELEMS + 1024);
    reinterpret_cast<float*>(ws)[BOUT_F32OFF + i4] = (i4 < NFEAT) ? bo[i4] * SSIG : 0.0f;
  } else if (idx < WFRAG_ELEMS + WOUT_ELEMS + 1024 + 16 + 1024) {
    int i5 = idx - (WFRAG_ELEMS + WOUT_ELEMS + 1024 + 16);
    int l = i5 >> 9, r = i5 & 511;
    int w = r >> 6, lg = (r >> 4) & 3, j16 = r & 15;
    int f = j16 >> 3, j = j16 & 7;
    int gate = f * 2 + (j >> 2);
    int dim  = w * 16 + lg * 4 + (j & 3);
    float v = l ? (bih1[gate * 128 + dim] + bhh1[gate * 128 + dim])
                : (bih0[gate * 128 + dim] + bhh0[gate * 128 + dim]);
    float sc = (gate == 2) ? STANH : SSIG;
    ws[BBF16_U16OFF + i5] = f2bf(v * sc);
  }
}

// ---------------- main: 256 blocks x 512 threads ------------------------------------
// R14 = R13 + PAIR FUSION: within each pair the two cells read the same two
// buffers with roles swapped, so the 8 activation fragments are loaded ONCE and
// each feeds 8 MFMAs (4 per cell). LDS reads/pair 36 -> 28; 8 independent acc
// chains interleave; merged VALU tails. Bias moved to the tail (acc init via
// MFMA inline C=0) to keep MFMA-phase register peak ~250 < 256.
__global__ void
__attribute__((amdgpu_flat_work_group_size(512, 512), amdgpu_waves_per_eu(2, 2)))
lstm_kernel(
    const float* __restrict__ ench, const float* __restrict__ encc,
    const unsigned short* __restrict__ wfrag, const unsigned short* __restrict__ woutf,
    const unsigned short* __restrict__ biasbf, const float* __restrict__ boutc,
    float* __restrict__ out)
{
  __shared__ __align__(16) unsigned char smem[SMEM_BYTES];
  bf16x8* wlds = reinterpret_cast<bf16x8*>(smem);
  unsigned short* act = reinterpret_cast<unsigned short*>(smem + ACT_OFF);

  const int tid  = threadIdx.x;
  const int wave = tid >> 6, lane = tid & 63;
  const int col  = lane & 15, lg = lane >> 4;
  const int n0   = blockIdx.x * ROWS;
  const int dbase = wave * 16 + lg * 4;

  const bf16x8* wfv = reinterpret_cast<const bf16x8*>(wfrag);

  // ---- persistent weight fragments: s=0..5 pinned chunk-by-chunk (R8 recipe) ----
  bf16x8 wreg[2][4][6];
  #pragma unroll
  for (int l = 0; l < 2; ++l)
    #pragma unroll
    for (int g = 0; g < 4; ++g) {
      #pragma unroll
      for (int s = 0; s < 6; ++s)
        wreg[l][g][s] = wfv[(size_t)((((l * 8 + wave) * 4 + g) * 8) + s) * 64 + lane];
      #pragma unroll
      for (int s = 0; s < 6; ++s) {
        f32x4 t_ = __builtin_bit_cast(f32x4, wreg[l][g][s]);
        asm volatile("" : "+v"(t_));
        wreg[l][g][s] = __builtin_bit_cast(bf16x8, t_);
      }
      __builtin_amdgcn_sched_barrier(0);
    }

  // ---- s=6..7 fragments -> LDS ----
  #pragma unroll
  for (int l = 0; l < 2; ++l)
    #pragma unroll
    for (int g = 0; g < 4; ++g)
      #pragma unroll
      for (int si = 0; si < 2; ++si)
        wlds[(((wave * 2 + l) * 4 + g) * 2 + si) * 64 + lane] =
            wfv[(size_t)((((l * 8 + wave) * 4 + g) * 8) + 6 + si) * 64 + lane];

  for (int i = tid; i < 2 * ROWS * LSTR; i += 512) act[i] = 0;
  for (int i = tid; i < ROWS * HDIM; i += 512) {
    int r = i >> 7, d = i & (HDIM - 1);
    act[(5 * ROWS + r) * LSTR + d] = f2bf(ench[(n0 + r) * HDIM + d]);
    act[(3 * ROWS + r) * LSTR + d] = f2bf(ench[(size_t)(NBATCH + n0 + r) * HDIM + d]);
  }
  for (int i = tid; i < 1024; i += 512)
    reinterpret_cast<unsigned short*>(smem + BIAS_OFF)[i] = biasbf[i];
  if (tid < 16) reinterpret_cast<float*>(smem + BOUT_OFF)[tid] = boutc[tid];
  f32x4 c0 = *reinterpret_cast<const f32x4*>(&encc[(size_t)(n0 + col) * HDIM + dbase]);
  f32x4 c1 = *reinterpret_cast<const f32x4*>(&encc[(size_t)(NBATCH + n0 + col) * HDIM + dbase]);
  __syncthreads();

  const int aoffl = col * LSTR + lg * 8;
  const int lb0 = (wave * 2 + 0) * 8;
  const int lb1 = (wave * 2 + 1) * 8;
  const bf16x8* wov = reinterpret_cast<const bf16x8*>(woutf);

  // activation tail: add bias (bf16<<16 exact) then shared-rcp activations; write h.
  auto tail = [&](f32x4& a0, f32x4& a1, f32x4& a2, f32x4& a3, int bl, int ob, f32x4& c) {
    const unsigned char* bptr = smem + BIAS_OFF + (size_t)(((bl * 8 + wave) * 4 + lg) * 32);
    bf16x8 bb0 = *reinterpret_cast<const bf16x8*>(bptr);
    bf16x8 bb1 = *reinterpret_cast<const bf16x8*>(bptr + 16);
    unsigned int hu[4];
    #pragma unroll
    for (int j = 0; j < 4; ++j) {
      float Ei = __builtin_amdgcn_exp2f(a0[j] + bf2f(bb0[j]));
      float Ef = __builtin_amdgcn_exp2f(a1[j] + bf2f(bb0[4 + j]));
      float Eg = __builtin_amdgcn_exp2f(fminf(a2[j] + bf2f(bb1[j]), 80.0f));
      float Eo = __builtin_amdgcn_exp2f(a3[j] + bf2f(bb1[4 + j]));
      float sf = __builtin_amdgcn_rcpf(1.0f + Ef);
      float rig = __builtin_amdgcn_rcpf((1.0f + Ei) * (1.0f + Eg));
      float cn = __builtin_fmaf(c[j], sf, (1.0f - Eg) * rig);
      c[j] = cn;
      float Ec = __builtin_amdgcn_exp2f(fminf(STANH * cn, 80.0f));
      float rr = __builtin_amdgcn_rcpf((1.0f + Eo) * (1.0f + Ec));
      hu[j] = f2bf((1.0f - Ec) * rr);
    }
    uint2* op = reinterpret_cast<uint2*>(act + ob * (ROWS * LSTR) + col * LSTR + dbase);
    *op = make_uint2(hu[0] | (hu[1] << 16), hu[2] | (hu[3] << 16));
  };

  // unfused cell (prologue / t=0 / t=180 tail)
  auto cellNB = [&](int xb, int hb, int ob, const bf16x8 (&wr)[4][6], int lb, int bl, f32x4& c) {
    const unsigned short* xp = act + xb * (ROWS * LSTR) + aoffl;
    const unsigned short* hp = act + hb * (ROWS * LSTR) + aoffl;
    const f32x4 z4 = {0.f, 0.f, 0.f, 0.f};
    f32x4 A0, A1, A2, A3;
    {
      bf16x8 b = *reinterpret_cast<const bf16x8*>(&xp[0]);
      A0 = MF(wr[0][0], b, z4); A1 = MF(wr[1][0], b, z4);
      A2 = MF(wr[2][0], b, z4); A3 = MF(wr[3][0], b, z4);
    }
    #pragma unroll
    for (int s = 1; s < 4; ++s) {
      bf16x8 b = *reinterpret_cast<const bf16x8*>(&xp[s * 32]);
      A0 = MF(wr[0][s], b, A0); A1 = MF(wr[1][s], b, A1);
      A2 = MF(wr[2][s], b, A2); A3 = MF(wr[3][s], b, A3);
    }
    #pragma unroll
    for (int s = 0; s < 2; ++s) {
      bf16x8 b = *reinterpret_cast<const bf16x8*>(&hp[s * 32]);
      A0 = MF(wr[0][4 + s], b, A0); A1 = MF(wr[1][4 + s], b, A1);
      A2 = MF(wr[2][4 + s], b, A2); A3 = MF(wr[3][4 + s], b, A3);
    }
    #pragma unroll
    for (int si = 0; si < 2; ++si) {
      bf16x8 b = *reinterpret_cast<const bf16x8*>(&hp[(2 + si) * 32]);
      bf16x8 w;
      w = wlds[(lb + 0 + si) * 64 + lane]; A0 = MF(w, b, A0);
      w = wlds[(lb + 2 + si) * 64 + lane]; A1 = MF(w, b, A1);
      w = wlds[(lb + 4 + si) * 64 + lane]; A2 = MF(w, b, A2);
      w = wlds[(lb + 6 + si) * 64 + lane]; A3 = MF(w, b, A3);
    }
    tail(A0, A1, A2, A3, bl, ob, c);
  };

  // fused pair: cellA{x=pb,h=qb,weights wrA} || cellB{x=qb,h=pb,weights wrB}
  // 8 shared fragment loads; 64 MFMAs over 8 independent acc chains; 2 tails.
  auto fusedPair = [&](int pb, int qb,
                       const bf16x8 (&wrA)[4][6], const bf16x8 (&wrB)[4][6],
                       int lbA, int lbB, int blA, int blB, int obA, int obB,
                       f32x4& cA, f32x4& cB) {
    const unsigned short* pp = act + pb * (ROWS * LSTR) + aoffl;
    const unsigned short* qp = act + qb * (ROWS * LSTR) + aoffl;
    const f32x4 z4 = {0.f, 0.f, 0.f, 0.f};
    f32x4 A0, A1, A2, A3, B0, B1, B2, B3;
    // s = 0 (init both acc sets)
    {
      bf16x8 fp = *reinterpret_cast<const bf16x8*>(&pp[0]);
      A0 = MF(wrA[0][0], fp, z4); A1 = MF(wrA[1][0], fp, z4);
      A2 = MF(wrA[2][0], fp, z4); A3 = MF(wrA[3][0], fp, z4);
      B0 = MF(wrB[0][4], fp, z4); B1 = MF(wrB[1][4], fp, z4);
      B2 = MF(wrB[2][4], fp, z4); B3 = MF(wrB[3][4], fp, z4);
      bf16x8 fq = *reinterpret_cast<const bf16x8*>(&qp[0]);
      B0 = MF(wrB[0][0], fq, B0); B1 = MF(wrB[1][0], fq, B1);
      B2 = MF(wrB[2][0], fq, B2); B3 = MF(wrB[3][0], fq, B3);
      A0 = MF(wrA[0][4], fq, A0); A1 = MF(wrA[1][4], fq, A1);
      A2 = MF(wrA[2][4], fq, A2); A3 = MF(wrA[3][4], fq, A3);
    }
    // s = 1 (reg h-weights)
    {
      bf16x8 fp = *reinterpret_cast<const bf16x8*>(&pp[32]);
      A0 = MF(wrA[0][1], fp, A0); A1 = MF(wrA[1][1], fp, A1);
      A2 = MF(wrA[2][1], fp, A2); A3 = MF(wrA[3][1], fp, A3);
      B0 = MF(wrB[0][5], fp, B0); B1 = MF(wrB[1][5], fp, B1);
      B2 = MF(wrB[2][5], fp, B2); B3 = MF(wrB[3][5], fp, B3);
      bf16x8 fq = *reinterpret_cast<const bf16x8*>(&qp[32]);
      B0 = MF(wrB[0][1], fq, B0); B1 = MF(wrB[1][1], fq, B1);
      B2 = MF(wrB[2][1], fq, B2); B3 = MF(wrB[3][1], fq, B3);
      A0 = MF(wrA[0][5], fq, A0); A1 = MF(wrA[1][5], fq, A1);
      A2 = MF(wrA[2][5], fq, A2); A3 = MF(wrA[3][5], fq, A3);
    }
    // s = 2,3 (LDS h-weights, streamed one at a time)
    #pragma unroll
    for (int si = 0; si < 2; ++si) {
      bf16x8 fp = *reinterpret_cast<const bf16x8*>(&pp[(2 + si) * 32]);
      A0 = MF(wrA[0][2 + si], fp, A0); A1 = MF(wrA[1][2 + si], fp, A1);
      A2 = MF(wrA[2][2 + si], fp, A2); A3 = MF(wrA[3][2 + si], fp, A3);
      bf16x8 w;
      w = wlds[(lbB + 0 + si) * 64 + lane]; B0 = MF(w, fp, B0);
      w = wlds[(lbB + 2 + si) * 64 + lane]; B1 = MF(w, fp, B1);
      w = wlds[(lbB + 4 + si) * 64 + lane]; B2 = MF(w, fp, B2);
      w = wlds[(lbB + 6 + si) * 64 + lane]; B3 = MF(w, fp, B3);
      bf16x8 fq = *reinterpret_cast<const bf16x8*>(&qp[(2 + si) * 32]);
      B0 = MF(wrB[0][2 + si], fq, B0); B1 = MF(wrB[1][2 + si], fq, B1);
      B2 = MF(wrB[2][2 + si], fq, B2); B3 = MF(wrB[3][2 + si], fq, B3);
      w = wlds[(lbA + 0 + si) * 64 + lane]; A0 = MF(w, fq, A0);
      w = wlds[(lbA + 2 + si) * 64 + lane]; A1 = MF(w, fq, A1);
      w = wlds[(lbA + 4 + si) * 64 + lane]; A2 = MF(w, fq, A2);
      w = wlds[(lbA + 6 + si) * 64 + lane]; A3 = MF(w, fq, A3);
    }
    tail(A0, A1, A2, A3, blA, obA, cA);
    tail(B0, B1, B2, B3, blB, obB, cB);
  };

  auto outproj = [&](int b0, int b1, int tt) {
    const unsigned short* z0 = act + b0 * (ROWS * LSTR) + aoffl;
    const unsigned short* z1 = act + b1 * (ROWS * LSTR) + aoffl;
    f32x4 po = *reinterpret_cast<const f32x4*>(smem + BOUT_OFF + lg * 16);
    #pragma unroll
    for (int s = 0; s < 4; ++s) {
      bf16x8 z = *reinterpret_cast<const bf16x8*>(&z0[s * 32]);
      po = MF(wov[s * 64 + lane], z, po);
    }
    #pragma unroll
    for (int s = 0; s < 4; ++s) {
      bf16x8 z = *reinterpret_cast<const bf16x8*>(&z1[s * 32]);
      po = MF(wov[(4 + s) * 64 + lane], z, po);
    }
    if (lg < 3) {
      f32x4 r;
      r[0] = fsig2(po[0]); r[1] = fsig2(po[1]); r[2] = fsig2(po[2]); r[3] = fsig2(po[3]);
      *reinterpret_cast<f32x4*>(&out[(size_t)(n0 + col) * OUTSTRIDE + tt * NFEAT + lg * 4]) = r;
    }
  };

  // ---- t = 0 (pair B asymmetric: h1 comes from buf3) ----
  cellNB(0, 5, 4, wreg[0], lb0, 0, c0);          // L0t0(0): x=buf0(0s), h=buf5 -> buf4
  FBAR();
  cellNB(1, 4, 5, wreg[0], lb0, 0, c0);          // L0t1(0): x=buf1(0s), h=buf4 -> buf5
  __builtin_amdgcn_sched_barrier(0);
  cellNB(4, 3, 2, wreg[1], lb1, 1, c1);          // L1t0(0): x=buf4, h=buf3 -> zA(0)=2
  FBAR();
  fusedPair(5, 2, wreg[1], wreg[0], lb1, lb0, 1, 0, 3, 4, c1, c0);  // A(0): L1t1(0)->3, L0t0(1)->4
  FBAR();

  for (int t = 1; t < SEQT; ++t) {
    const int xA = (t & 1) ? 2 : 0, xB = xA + 1;
    const int zA = (t & 1) ? 0 : 2, zB = zA + 1;
    // pair B(t): L0t1(t){x=xB,h=4}->5 || L1t0(t){x=4,h=xB}->zA ; outproj(t-1) on wave0
    fusedPair(xB, 4, wreg[0], wreg[1], lb0, lb1, 0, 1, 5, zA, c0, c1);
    if (wave == 0) outproj(xA, xB, t - 1);       // zA(t-1)=xA, zB(t-1)=xB
    FBAR();
    if (t + 1 < SEQT) {
      // pair A(t): L1t1(t){x=5,h=zA}->zB || L0t0(t+1){x=zA,h=5}->4
      fusedPair(5, zA, wreg[1], wreg[0], lb1, lb0, 1, 0, zB, 4, c1, c0);
    } else {
      cellNB(5, zA, zB, wreg[1], lb1, 1, c1);    // L1t1(180) solo
    }
    FBAR();
  }
  if (wave == 0) outproj(2, 3, SEQT - 1);        // zA(180)=2, zB(180)=3
}

extern "C" void kernel_launch(void* const* d_in, const int* in_sizes, int n_in,
                              void* d_out, int out_size, void* d_ws, size_t ws_size,
                              hipStream_t stream) {
  const float* ench = (const float*)d_in[0];
  const float* encc = (const float*)d_in[1];
  const float* Wih0 = (const float*)d_in[2];
  const float* Whh0 = (const float*)d_in[3];
  const float* bih0 = (const float*)d_in[4];
  const float* bhh0 = (const float*)d_in[5];
  const float* Wih1 = (const float*)d_in[6];
  const float* Whh1 = (const float*)d_in[7];
  const float* bih1 = (const float*)d_in[8];
  const float* bhh1 = (const float*)d_in[9];
  const float* Wo   = (const float*)d_in[10];
  const float* bo   = (const float*)d_in[11];
  unsigned short* ws = (unsigned short*)d_ws;

  int total = WFRAG_ELEMS + WOUT_ELEMS + 1024 + 16 + 1024;
  int blocks = (total + 511) / 512;
  hipLaunchKernelGGL(setup_kernel, dim3(blocks), dim3(512), 0, stream,
                     Wih0, Whh0, bih0, bhh0, Wih1, Whh1, bih1, bhh1, Wo, bo, ws);

  const unsigned short* wfrag  = ws;
  const unsigned short* woutf  = ws + WFRAG_ELEMS;
  const unsigned short* biasbf = ws + BBF16_U16OFF;
  const float* boutc = reinterpret_cast<const float*>(ws) + BOUT_F32OFF;

  hipLaunchKernelGGL(lstm_kernel, dim3(NBATCH / ROWS), dim3(512), 0, stream,
                     ench, encc, wfrag, woutf, biasbf, boutc, (float*)d_out);
}

// Round 15
// 792.246 us; speedup vs baseline: 1.2517x; 1.2517x over previous
//
#include <hip/hip_runtime.h>
#include <hip/hip_bf16.h>

typedef __attribute__((ext_vector_type(8))) short bf16x8;
typedef __attribute__((ext_vector_type(4))) float f32x4;

#define NBATCH 4096
#define SEQT 181
#define NFEAT 12
#define HDIM 128
#define ROWS 16
#define LSTR 136              // padded bf16 row stride
#define OUTSTRIDE (SEQT*NFEAT)

// d_ws layout (ushort units):
#define WFRAG_ELEMS 262144
#define WOUT_ELEMS  4096
#define BIAS_F32OFF (532480/4)     // legacy, unused
#define BOUT_F32OFF (536576/4)     // pre-scaled by -log2e
#define BBF16_U16OFF 268320        // bf16-packed PRE-SCALED bias [l][wave][lg][16]

// LDS byte offsets
#define ACT_OFF  131072
#define BIAS_OFF 157184
#define BOUT_OFF 161280
#define SMEM_BYTES 161344

#define SSIG (-1.442695041f)
#define STANH (-2.885390082f)

#define FBAR() asm volatile("s_waitcnt lgkmcnt(0)\n\ts_barrier" ::: "memory")

__device__ __forceinline__ float fsig2(float xs) {
  return __builtin_amdgcn_rcpf(1.0f + __builtin_amdgcn_exp2f(xs));
}
__device__ __forceinline__ unsigned short f2bf(float x) {
  __hip_bfloat16 h = __float2bfloat16(x);
  return __builtin_bit_cast(unsigned short, h);
}

// ---------------- setup: repack weights into MFMA fragment order (bf16), pre-scaled ----------------
__global__ void setup_kernel(const float* __restrict__ Wih0, const float* __restrict__ Whh0,
                             const float* __restrict__ bih0, const float* __restrict__ bhh0,
                             const float* __restrict__ Wih1, const float* __restrict__ Whh1,
                             const float* __restrict__ bih1, const float* __restrict__ bhh1,
                             const float* __restrict__ Wo,   const float* __restrict__ bo,
                             unsigned short* __restrict__ ws)
{
  int idx = blockIdx.x * blockDim.x + threadIdx.x;
  if (idx < WFRAG_ELEMS) {
    int e = idx & 7, lane = (idx >> 3) & 63, s = (idx >> 9) & 7, g = (idx >> 12) & 3,
        w = (idx >> 14) & 7, l = idx >> 17;
    int row = g * 128 + w * 16 + (lane & 15);
    int k   = s * 32 + (lane >> 4) * 8 + e;
    const float* Wih = l ? Wih1 : Wih0;
    const float* Whh = l ? Whh1 : Whh0;
    float v = (k < HDIM) ? Wih[row * HDIM + k] : Whh[row * HDIM + (k - HDIM)];
    float sc = (g == 2) ? STANH : SSIG;
    ws[idx] = f2bf(v * sc);
  } else if (idx < WFRAG_ELEMS + WOUT_ELEMS) {
    int i2 = idx - WFRAG_ELEMS;
    int e = i2 & 7, lane = (i2 >> 3) & 63, s = i2 >> 9;
    int c = lane & 15;
    int k = s * 32 + (lane >> 4) * 8 + e;
    float v = (c < NFEAT) ? Wo[c * 256 + k] * SSIG : 0.0f;
    ws[idx] = f2bf(v);
  } else if (idx < WFRAG_ELEMS + WOUT_ELEMS + 1024) {
    int i3 = idx - (WFRAG_ELEMS + WOUT_ELEMS);
    int l = i3 >> 9, r = i3 & 511;
    float v = l ? (bih1[r] + bhh1[r]) : (bih0[r] + bhh0[r]);
    reinterpret_cast<float*>(ws)[BIAS_F32OFF + i3] = v;
  } else if (idx < WFRAG_ELEMS + WOUT_ELEMS + 1024 + 16) {
    int i4 = idx - (WFRAG_ELEMS + WOUT_ELEMS + 1024);
    reinterpret_cast<float*>(ws)[BOUT_F32OFF + i4] = (i4 < NFEAT) ? bo[i4] * SSIG : 0.0f;
  } else if (idx < WFRAG_ELEMS + WOUT_ELEMS + 1024 + 16 + 1024) {
    int i5 = idx - (WFRAG_ELEMS + WOUT_ELEMS + 1024 + 16);
    int l = i5 >> 9, r = i5 & 511;
    int w = r >> 6, lg = (r >> 4) & 3, j16 = r & 15;
    int f = j16 >> 3, j = j16 & 7;
    int gate = f * 2 + (j >> 2);
    int dim  = w * 16 + lg * 4 + (j & 3);
    float v = l ? (bih1[gate * 128 + dim] + bhh1[gate * 128 + dim])
                : (bih0[gate * 128 + dim] + bhh0[gate * 128 + dim]);
    float sc = (gate == 2) ? STANH : SSIG;
    ws[BBF16_U16OFF + i5] = f2bf(v * sc);
  }
}

// ---------------- main: 256 blocks x 512 threads ------------------------------------
// R15 = R13 revert (best: 791us). R14's 8-acc fusion spilled accumulators
// (WRITE +27MB); the proven working-set budget above the 192 pinned weight regs
// is ~4 acc chains. R13 is the empirically optimal point of this structure:
// weights CU-resident (VGPR+LDS packed to capacity), 18 LDS reads/cell (floor),
// paired cells (363 barriers), pre-scaled weights + shared-rcp activations.
__global__ void
__attribute__((amdgpu_flat_work_group_size(512, 512), amdgpu_waves_per_eu(2, 2)))
lstm_kernel(
    const float* __restrict__ ench, const float* __restrict__ encc,
    const unsigned short* __restrict__ wfrag, const unsigned short* __restrict__ woutf,
    const unsigned short* __restrict__ biasbf, const float* __restrict__ boutc,
    float* __restrict__ out)
{
  __shared__ __align__(16) unsigned char smem[SMEM_BYTES];
  bf16x8* wlds = reinterpret_cast<bf16x8*>(smem);
  unsigned short* act = reinterpret_cast<unsigned short*>(smem + ACT_OFF);

  const int tid  = threadIdx.x;
  const int wave = tid >> 6, lane = tid & 63;
  const int col  = lane & 15, lg = lane >> 4;
  const int n0   = blockIdx.x * ROWS;
  const int dbase = wave * 16 + lg * 4;

  const bf16x8* wfv = reinterpret_cast<const bf16x8*>(wfrag);

  // ---- persistent weight fragments: s=0..5 pinned chunk-by-chunk (R8 recipe) ----
  bf16x8 wreg[2][4][6];
  #pragma unroll
  for (int l = 0; l < 2; ++l)
    #pragma unroll
    for (int g = 0; g < 4; ++g) {
      #pragma unroll
      for (int s = 0; s < 6; ++s)
        wreg[l][g][s] = wfv[(size_t)((((l * 8 + wave) * 4 + g) * 8) + s) * 64 + lane];
      #pragma unroll
      for (int s = 0; s < 6; ++s) {
        f32x4 t_ = __builtin_bit_cast(f32x4, wreg[l][g][s]);
        asm volatile("" : "+v"(t_));
        wreg[l][g][s] = __builtin_bit_cast(bf16x8, t_);
      }
      __builtin_amdgcn_sched_barrier(0);
    }

  // ---- s=6..7 fragments -> LDS ----
  #pragma unroll
  for (int l = 0; l < 2; ++l)
    #pragma unroll
    for (int g = 0; g < 4; ++g)
      #pragma unroll
      for (int si = 0; si < 2; ++si)
        wlds[(((wave * 2 + l) * 4 + g) * 2 + si) * 64 + lane] =
            wfv[(size_t)((((l * 8 + wave) * 4 + g) * 8) + 6 + si) * 64 + lane];

  // zero x-ping buffers 0,1 (dec_in0 = 0)
  for (int i = tid; i < 2 * ROWS * LSTR; i += 512) act[i] = 0;
  // initial h0 -> buf5 ; initial h1 -> buf3 (read once by L1t0(0), overwritten later)
  for (int i = tid; i < ROWS * HDIM; i += 512) {
    int r = i >> 7, d = i & (HDIM - 1);
    act[(5 * ROWS + r) * LSTR + d] = f2bf(ench[(n0 + r) * HDIM + d]);
    act[(3 * ROWS + r) * LSTR + d] = f2bf(ench[(size_t)(NBATCH + n0 + r) * HDIM + d]);
  }
  for (int i = tid; i < 1024; i += 512)
    reinterpret_cast<unsigned short*>(smem + BIAS_OFF)[i] = biasbf[i];
  if (tid < 16) reinterpret_cast<float*>(smem + BOUT_OFF)[tid] = boutc[tid];
  f32x4 c0 = *reinterpret_cast<const f32x4*>(&encc[(size_t)(n0 + col) * HDIM + dbase]);
  f32x4 c1 = *reinterpret_cast<const f32x4*>(&encc[(size_t)(NBATCH + n0 + col) * HDIM + dbase]);
  __syncthreads();   // init barrier: full drain

  const int aoffl = col * LSTR + lg * 8;

  // streamed cell WITHOUT trailing barrier (barriers are per-pair in the loop)
  auto cellNB = [&](int xb, int hb, int ob, const bf16x8 (&wr)[4][6], int lb, int bl, f32x4& c) {
    const unsigned short* xp = act + xb * (ROWS * LSTR) + aoffl;
    const unsigned short* hp = act + hb * (ROWS * LSTR) + aoffl;
    const unsigned char* bptr = smem + BIAS_OFF + (size_t)(((bl * 8 + wave) * 4 + lg) * 32);
    bf16x8 bb0 = *reinterpret_cast<const bf16x8*>(bptr);
    bf16x8 bb1 = *reinterpret_cast<const bf16x8*>(bptr + 16);
    f32x4 acc0, acc1, acc2, acc3;
    #pragma unroll
    for (int j = 0; j < 4; ++j) {
      acc0[j] = __builtin_bit_cast(float, ((unsigned)(unsigned short)bb0[j]) << 16);
      acc1[j] = __builtin_bit_cast(float, ((unsigned)(unsigned short)bb0[4 + j]) << 16);
      acc2[j] = __builtin_bit_cast(float, ((unsigned)(unsigned short)bb1[j]) << 16);
      acc3[j] = __builtin_bit_cast(float, ((unsigned)(unsigned short)bb1[4 + j]) << 16);
    }
    #pragma unroll
    for (int s = 0; s < 4; ++s) {                       // k = x-half (reg weights)
      bf16x8 b = *reinterpret_cast<const bf16x8*>(&xp[s * 32]);
      acc0 = __builtin_amdgcn_mfma_f32_16x16x32_bf16(wr[0][s], b, acc0, 0, 0, 0);
      acc1 = __builtin_amdgcn_mfma_f32_16x16x32_bf16(wr[1][s], b, acc1, 0, 0, 0);
      acc2 = __builtin_amdgcn_mfma_f32_16x16x32_bf16(wr[2][s], b, acc2, 0, 0, 0);
      acc3 = __builtin_amdgcn_mfma_f32_16x16x32_bf16(wr[3][s], b, acc3, 0, 0, 0);
    }
    #pragma unroll
    for (int s = 0; s < 2; ++s) {                       // k = h-half, reg weights
      bf16x8 b = *reinterpret_cast<const bf16x8*>(&hp[s * 32]);
      acc0 = __builtin_amdgcn_mfma_f32_16x16x32_bf16(wr[0][4 + s], b, acc0, 0, 0, 0);
      acc1 = __builtin_amdgcn_mfma_f32_16x16x32_bf16(wr[1][4 + s], b, acc1, 0, 0, 0);
      acc2 = __builtin_amdgcn_mfma_f32_16x16x32_bf16(wr[2][4 + s], b, acc2, 0, 0, 0);
      acc3 = __builtin_amdgcn_mfma_f32_16x16x32_bf16(wr[3][4 + s], b, acc3, 0, 0, 0);
    }
    #pragma unroll
    for (int si = 0; si < 2; ++si) {                    // k = h-half tail, LDS weights
      bf16x8 b = *reinterpret_cast<const bf16x8*>(&hp[(2 + si) * 32]);
      bf16x8 w0 = wlds[(lb + 0 * 2 + si) * 64 + lane];
      bf16x8 w1 = wlds[(lb + 1 * 2 + si) * 64 + lane];
      bf16x8 w2 = wlds[(lb + 2 * 2 + si) * 64 + lane];
      bf16x8 w3 = wlds[(lb + 3 * 2 + si) * 64 + lane];
      acc0 = __builtin_amdgcn_mfma_f32_16x16x32_bf16(w0, b, acc0, 0, 0, 0);
      acc1 = __builtin_amdgcn_mfma_f32_16x16x32_bf16(w1, b, acc1, 0, 0, 0);
      acc2 = __builtin_amdgcn_mfma_f32_16x16x32_bf16(w2, b, acc2, 0, 0, 0);
      acc3 = __builtin_amdgcn_mfma_f32_16x16x32_bf16(w3, b, acc3, 0, 0, 0);
    }
    unsigned int hu[4];
    #pragma unroll
    for (int j = 0; j < 4; ++j) {
      float Ei = __builtin_amdgcn_exp2f(acc0[j]);
      float Ef = __builtin_amdgcn_exp2f(acc1[j]);
      float Eg = __builtin_amdgcn_exp2f(fminf(acc2[j], 80.0f));
      float Eo = __builtin_amdgcn_exp2f(acc3[j]);
      float sf = __builtin_amdgcn_rcpf(1.0f + Ef);
      float rig = __builtin_amdgcn_rcpf((1.0f + Ei) * (1.0f + Eg));
      float cn = __builtin_fmaf(c[j], sf, (1.0f - Eg) * rig);
      c[j] = cn;
      float Ec = __builtin_amdgcn_exp2f(fminf(STANH * cn, 80.0f));
      float rr = __builtin_amdgcn_rcpf((1.0f + Eo) * (1.0f + Ec));
      hu[j] = f2bf((1.0f - Ec) * rr);
    }
    uint2* op = reinterpret_cast<uint2*>(act + ob * (ROWS * LSTR) + col * LSTR + dbase);
    *op = make_uint2(hu[0] | (hu[1] << 16), hu[2] | (hu[3] << 16));
  };

  const int lb0 = (wave * 2 + 0) * 8;
  const int lb1 = (wave * 2 + 1) * 8;
  const bf16x8* wov = reinterpret_cast<const bf16x8*>(woutf);

  // out-projection for step tt, reading z halves from bufs b0,b1 (wave0 only)
  auto outproj = [&](int b0, int b1, int tt) {
    const unsigned short* z0 = act + b0 * (ROWS * LSTR) + aoffl;
    const unsigned short* z1 = act + b1 * (ROWS * LSTR) + aoffl;
    f32x4 po = *reinterpret_cast<const f32x4*>(smem + BOUT_OFF + lg * 16);
    #pragma unroll
    for (int s = 0; s < 4; ++s) {
      bf16x8 z = *reinterpret_cast<const bf16x8*>(&z0[s * 32]);
      po = __builtin_amdgcn_mfma_f32_16x16x32_bf16(wov[s * 64 + lane], z, po, 0, 0, 0);
    }
    #pragma unroll
    for (int s = 0; s < 4; ++s) {
      bf16x8 z = *reinterpret_cast<const bf16x8*>(&z1[s * 32]);
      po = __builtin_amdgcn_mfma_f32_16x16x32_bf16(wov[(4 + s) * 64 + lane], z, po, 0, 0, 0);
    }
    if (lg < 3) {
      f32x4 r;
      r[0] = fsig2(po[0]); r[1] = fsig2(po[1]); r[2] = fsig2(po[2]); r[3] = fsig2(po[3]);
      *reinterpret_cast<f32x4*>(&out[(size_t)(n0 + col) * OUTSTRIDE + tt * NFEAT + lg * 4]) = r;
    }
  };

  // prologue: L0t0(0)  (x=buf0 zeros, h=buf5)
  cellNB(0, 5, 4, wreg[0], lb0, 0, c0);
  FBAR();

  for (int t = 0; t < SEQT; ++t) {
    const int xA = (t & 1) ? 2 : 0, xB = xA + 1;
    const int zA = (t & 1) ? 0 : 2, zB = zA + 1;
    // ---- pair B(t): L0t1(t) || L1t0(t)  (+ out-proj(t-1) on wave0) ----
    cellNB(xB, 4, 5, wreg[0], lb0, 0, c0);            // L0t1: x=xB, h=buf4 -> buf5
    __builtin_amdgcn_sched_barrier(0);
    cellNB(4, (t == 0) ? 3 : xB, zA, wreg[1], lb1, 1, c1);  // L1t0: x=buf4 -> zA
    if (wave == 0 && t > 0) outproj(xA, xB, t - 1);   // zA(t-1)=xA, zB(t-1)=xB
    FBAR();
    // ---- pair A(t): L1t1(t) || L0t0(t+1) ----
    cellNB(5, zA, zB, wreg[1], lb1, 1, c1);           // L1t1: x=buf5, h=zA -> zB
    __builtin_amdgcn_sched_barrier(0);
    if (t + 1 < SEQT)
      cellNB(zA, 5, 4, wreg[0], lb0, 0, c0);          // L0t0(t+1): x=zA, h=buf5 -> buf4
    FBAR();
  }
  // epilogue: out-proj(180); zA(180)=2, zB(180)=3 (t=180 even), still intact
  if (wave == 0) outproj(2, 3, SEQT - 1);
}

extern "C" void kernel_launch(void* const* d_in, const int* in_sizes, int n_in,
                              void* d_out, int out_size, void* d_ws, size_t ws_size,
                              hipStream_t stream) {
  const float* ench = (const float*)d_in[0];
  const float* encc = (const float*)d_in[1];
  const float* Wih0 = (const float*)d_in[2];
  const float* Whh0 = (const float*)d_in[3];
  const float* bih0 = (const float*)d_in[4];
  const float* bhh0 = (const float*)d_in[5];
  const float* Wih1 = (const float*)d_in[6];
  const float* Whh1 = (const float*)d_in[7];
  const float* bih1 = (const float*)d_in[8];
  const float* bhh1 = (const float*)d_in[9];
  const float* Wo   = (const float*)d_in[10];
  const float* bo   = (const float*)d_in[11];
  unsigned short* ws = (unsigned short*)d_ws;

  int total = WFRAG_ELEMS + WOUT_ELEMS + 1024 + 16 + 1024;
  int blocks = (total + 511) / 512;
  hipLaunchKernelGGL(setup_kernel, dim3(blocks), dim3(512), 0, stream,
                     Wih0, Whh0, bih0, bhh0, Wih1, Whh1, bih1, bhh1, Wo, bo, ws);

  const unsigned short* wfrag  = ws;
  const unsigned short* woutf  = ws + WFRAG_ELEMS;
  const unsigned short* biasbf = ws + BBF16_U16OFF;
  const float* boutc = reinterpret_cast<const float*>(ws) + BOUT_F32OFF;

  hipLaunchKernelGGL(lstm_kernel, dim3(NBATCH / ROWS), dim3(512), 0, stream,
                     ench, encc, wfrag, woutf, biasbf, boutc, (float*)d_out);
}